// Round 2
// 201.604 us; speedup vs baseline: 1.0220x; 1.0220x over previous
//
#include <hip/hip_runtime.h>

#define B_    8
#define C_    64
#define H_    128
#define W_    128
#define K_    9
#define J_    18     // 2*K
#define COUT_ 64
#define TPX   16     // pixels per block
#define CK    576    // C_*K_
#define SROW  584    // sbuf row stride (bf16 elems)
#define NW81  (C_ * 81)                 // 5184 packed weight words
#define L2E   1.4426950408889634f       // log2(e), folded into conv weights+bias

typedef __attribute__((ext_vector_type(8))) short short8;
typedef __attribute__((ext_vector_type(4))) float float4v;
typedef __attribute__((ext_vector_type(2))) float f32x2;

// round-to-nearest-even fp32 -> bf16
__device__ __forceinline__ unsigned short f2bf(float f) {
    unsigned int u = __float_as_uint(f);
    u = u + 0x7fffu + ((u >> 16) & 1u);
    return (unsigned short)(u >> 16);
}

// conv tap (r*3+s) -> strip index r*7+s. constexpr everywhere (round 3:
// runtime-indexed S[] -> scratch demotion -> GB-scale spill).
constexpr int TMAP[9] = {0, 1, 2, 7, 8, 9, 14, 15, 16};

// -------- pre-kernel: NCHW -> NHWC transpose of x into workspace --------
__global__ __launch_bounds__(256)
void nchw_to_nhwc(const float* __restrict__ x, float* __restrict__ xt) {
    __shared__ float tile[64][65];
    const int bid = blockIdx.x;          // b*256 + h*2 + wt
    const int wt  = bid & 1;
    const int h   = (bid >> 1) & 127;
    const int b   = bid >> 8;
    const int w0  = wt << 6;
    const int q   = threadIdx.x >> 6;
    const int l   = threadIdx.x & 63;
    #pragma unroll
    for (int r = 0; r < 16; r++) {
        const int c = q * 16 + r;
        tile[c][l] = x[((size_t)(b * C_ + c) * H_ + h) * W_ + w0 + l];
    }
    __syncthreads();
    #pragma unroll
    for (int r = 0; r < 16; r++) {
        const int w = q * 16 + r;
        xt[((size_t)(b * H_ + h) * W_ + w0 + w) * C_ + l] = tile[l][w];
    }
}

// -------- pre-kernel: dw f32->bf16 AND offset-weight pair-pack ----------
// Blocks [0,144): dwb[i] = bf16(dw[i]).
// Blocks [144,165): owp word (c, k, t) = pack(bf16(L2E*w[c][2k][t]),
//                                             bf16(L2E*w[c][2k+1][t]))
// i.e. the (dy,dx) weight pair of tap t — enables v_pk_fma_f32 in the conv
// with f32x2 (dy,dx) accumulators, and folds log2(e) so the softmax uses
// v_exp_f32 (exp2) with no per-element multiply.
__global__ __launch_bounds__(256)
void prep_weights(const float* __restrict__ dw, unsigned short* __restrict__ dwb,
                  const float* __restrict__ ow, unsigned int* __restrict__ owp) {
    const int bid = blockIdx.x;
    const int dwblocks = (CK * COUT_) / 256;   // 144, exact
    if (bid < dwblocks) {
        const int i = bid * 256 + threadIdx.x;
        dwb[i] = f2bf(dw[i]);
    } else {
        const int i = (bid - dwblocks) * 256 + threadIdx.x;
        if (i < NW81) {
            const int c = i / 81, r = i - c * 81;
            const int k = r / 9,  t = r - k * 9;
            const float* s = ow + c * 162 + k * 18 + t;   // (2k)*9 = k*18
            owp[i] = (unsigned int)f2bf(s[0] * L2E) |
                     ((unsigned int)f2bf(s[9] * L2E) << 16);
        }
    }
}

// ---- conv inner loop: full unroll via template recursion (pragma-unroll
// bailed at this size in round 3 -> scratch). Word T = k*9 + t holds the
// bf16 (dy,dx) weight pair of output-pair k, tap t. One v_pk_fma_f32 per
// pixel per word: 81*(2 unpack + 4 pk_fma) vs 81*(2+8 scalar) before.
template<int T>
__device__ __forceinline__ void conv_steps(const unsigned int* __restrict__ owc,
                                           const float (&S)[28], f32x2 (&v2)[4][9]) {
    if constexpr (T < 81) {
        const unsigned int pw = owc[T];
        const f32x2 w2 = {__uint_as_float(pw << 16),
                          __uint_as_float(pw & 0xffff0000u)};
        constexpr int k = T / 9;
        constexpr int p = TMAP[T % 9];
        #pragma unroll
        for (int px = 0; px < 4; px++) {
            const float s = S[p + px];
            v2[px][k] = __builtin_elementwise_fma(w2, (f32x2){s, s}, v2[px][k]);
        }
        conv_steps<T + 1>(owc, S, v2);
    }
}

// ---- per-pixel bilinear taps ----
// NOTE (round-1 lesson): dy/dx are bilinear SAMPLE COORDINATES, not linear
// coefficients — the sampled value has a dy*dx cross term and a constant
// term, so softmax's 1/sum does NOT commute through the einsum. Normalize
// here, per pixel, via v_rcp_f32 (1-ulp approx, invisible under bf16).
template<int I>
__device__ __forceinline__ void taps_px(const f32x2 (&w)[9], const float inv,
                                        const float (&S)[28],
                                        unsigned short* __restrict__ sb) {
    #pragma unroll
    for (int k = 0; k < 9; k++) {
        const float dy = w[k].x * inv;
        const float dx = w[k].y * inv;
        const int base = TMAP[k] + I;              // constexpr-folded
        const float a  = S[base],     bb = S[base + 1];
        const float c  = S[base + 7], dd = S[base + 8];
        const float top = fmaf(dx, bb - a, a);
        const float bot = fmaf(dx, dd - c, c);
        sb[k] = f2bf(fmaf(dy, bot - top, top));
    }
}

// -------- fused kernel --------
// (256,3): budget ~168 regs; (256,4)'s 128-budget forced spills (rounds 5/6).
template<bool NHWC, bool PREB, bool PREP>
__global__ __launch_bounds__(256, 3)
void dcn_fused(const float* __restrict__ xsrc,
               const float* __restrict__ ow,
               const unsigned int* __restrict__ owp,
               const float* __restrict__ ob,
               const float* __restrict__ dw,
               const unsigned short* __restrict__ dwb,
               const float* __restrict__ db,
               float* __restrict__ out) {
    // LDS union: ow_s (20736 B) is dead once conv_steps finishes; sbuf
    // (18688 B) reuses the same storage behind an extra barrier.
    // Total LDS 39424 -> 20736 B.
    static_assert(TPX * SROW * sizeof(unsigned short) <= NW81 * sizeof(unsigned int), "union");
    __shared__ __align__(16) unsigned int smem[NW81];
    unsigned int* ow_s = smem;
    unsigned short* sbuf = (unsigned short*)smem;

    const int tid  = threadIdx.x;
    const int wave = tid >> 6;
    const int lane = tid & 63;

    const int bid = blockIdx.x;
    const int b   = bid >> 10;
    const int rem = bid & 1023;
    const int h   = rem >> 3;
    const int w0  = (rem & 7) << 4;

    // stage packed offset weights
    if (PREP) {
        #pragma unroll
        for (int i = 0; i < 21; i++) {               // 5184 = 20*256 + 64
            const int idx = tid + i * 256;
            if (idx < NW81) ow_s[idx] = owp[idx];    // coalesced u32 copy
        }
    } else {
        for (int i = tid; i < NW81; i += 256) {      // fallback: pack in-kernel
            const int c = i / 81, r = i - c * 81;
            const int k = r / 9,  t = r - k * 9;
            const float* s = ow + c * 162 + k * 18 + t;
            ow_s[i] = (unsigned int)f2bf(s[0] * L2E) |
                      ((unsigned int)f2bf(s[9] * L2E) << 16);
        }
    }
    __syncthreads();

    // ---- phase A: conv + softmax + bilinear, 4 px per wave ----
    const int wbase = w0 + (wave << 2);
    const unsigned int* owc = ow_s + lane * 81;

    // wave strip = 4 rows x 7 cols (wbase-1 .. wbase+5)
    float S[28];
    if (h >= 1 && h <= H_ - 3 && wbase >= 1 && wbase <= W_ - 6) {
        // interior fast path: bounds are wave-uniform -> scalar branch,
        // no clamps / cndmasks on >95% of waves
        const float* p0 = NHWC
            ? xsrc + ((size_t)(b * H_ + (h - 1)) * W_ + (wbase - 1)) * C_ + lane
            : xsrc + ((size_t)(b * C_ + lane) * H_ + (h - 1)) * W_ + (wbase - 1);
        const int rs = NHWC ? (W_ * C_) : W_;
        const int cs = NHWC ? C_ : 1;
        #pragma unroll
        for (int r = 0; r < 4; r++)
            #pragma unroll
            for (int s = 0; s < 7; s++)
                S[r * 7 + s] = p0[r * rs + s * cs];
    } else {
        #pragma unroll
        for (int r = 0; r < 4; r++) {
            const int y = h - 1 + r;
            const bool yv = (unsigned)y < (unsigned)H_;
            #pragma unroll
            for (int s = 0; s < 7; s++) {
                const int xx = wbase - 1 + s;
                const bool ok = yv && ((unsigned)xx < (unsigned)W_);
                const float* p = NHWC
                    ? xsrc + ((size_t)(b * H_ + (y & 127)) * W_ + (xx & 127)) * C_ + lane
                    : xsrc + ((size_t)(b * C_ + lane) * H_ + (y & 127)) * W_ + (xx & 127);
                S[r * 7 + s] = ok ? *p : 0.0f;
            }
        }
    }

    // accumulators: v2[px][k] = L2E * (logit_dy, logit_dx) of tap k
    f32x2 v2[4][9];
    const float2* obp = (const float2*)(ob + lane * J_);
    #pragma unroll
    for (int p = 0; p < 9; p++) {
        const float2 f = obp[p];                     // bias, L1-hot (4.6 KB)
        const f32x2 b2 = {f.x * L2E, f.y * L2E};
        v2[0][p] = b2; v2[1][p] = b2; v2[2][p] = b2; v2[3][p] = b2;
    }
    conv_steps<0>(owc, S, v2);

    // exp2 + per-px local sums (registers only -> safe before union barrier).
    // No max-subtraction: logits bounded (|w|~0.05 scale), exp2 args ~ +-15,
    // fp32-safe.
    float psum[4];
    #pragma unroll
    for (int px = 0; px < 4; px++) {
        float s = 0.0f;
        #pragma unroll
        for (int k = 0; k < 9; k++) {
            f32x2 e;
            e.x = __builtin_amdgcn_exp2f(v2[px][k].x);
            e.y = __builtin_amdgcn_exp2f(v2[px][k].y);
            v2[px][k] = e;
            s += e.x + e.y;
        }
        psum[px] = s;
    }

    __syncthreads();   // all waves done reading ow_s -> smem becomes sbuf

    // cross-lane softmax denominators (sum over 64 lanes x 18 = full channel
    // axis), 4 px interleaved (4x ILP on the chain); xor<32 via single-inst
    // ds_swizzle (lane-shuffle through DS pipe, no LDS memory), xor32 via shfl.
    #pragma unroll
    for (int px = 0; px < 4; px++) psum[px] += __shfl_xor(psum[px], 32, 64);
#define RED_LEVEL(PAT) do { \
        const float r0_ = __uint_as_float((unsigned)__builtin_amdgcn_ds_swizzle((int)__float_as_uint(psum[0]), (PAT))); \
        const float r1_ = __uint_as_float((unsigned)__builtin_amdgcn_ds_swizzle((int)__float_as_uint(psum[1]), (PAT))); \
        const float r2_ = __uint_as_float((unsigned)__builtin_amdgcn_ds_swizzle((int)__float_as_uint(psum[2]), (PAT))); \
        const float r3_ = __uint_as_float((unsigned)__builtin_amdgcn_ds_swizzle((int)__float_as_uint(psum[3]), (PAT))); \
        psum[0] += r0_; psum[1] += r1_; psum[2] += r2_; psum[3] += r3_; \
    } while (0)
    RED_LEVEL(0x401F);   // xor 16
    RED_LEVEL(0x201F);   // xor 8
    RED_LEVEL(0x101F);   // xor 4
    RED_LEVEL(0x081F);   // xor 2
    RED_LEVEL(0x041F);   // xor 1
#undef RED_LEVEL

    const float inv0 = __builtin_amdgcn_rcpf(psum[0]);
    const float inv1 = __builtin_amdgcn_rcpf(psum[1]);
    const float inv2 = __builtin_amdgcn_rcpf(psum[2]);
    const float inv3 = __builtin_amdgcn_rcpf(psum[3]);

    unsigned short* sb = sbuf + (wave << 2) * SROW + lane * K_;
    taps_px<0>(v2[0], inv0, S, sb);
    taps_px<1>(v2[1], inv1, S, sb + SROW);
    taps_px<2>(v2[2], inv2, S, sb + 2 * SROW);
    taps_px<3>(v2[3], inv3, S, sb + 3 * SROW);

    __syncthreads();

    // ---- phase B: MFMA einsum. Per wave: 16 px x 16 outs, K=576 ----
    const int quad = lane >> 4;
    const int o    = (wave << 4) + (lane & 15);
    float4v acc = {0.f, 0.f, 0.f, 0.f};
    const unsigned short* arow = sbuf + (lane & 15) * SROW + quad * 8;
    #pragma unroll
    for (int t = 0; t < 18; t++) {
        short8 afrag = *(const short8*)(arow + t * 32);
        short8 bfrag;
        if (PREB) {
            bfrag = *(const short8*)(dwb + (size_t)o * CK + quad * 8 + t * 32);
        } else {
            const float* brow = dw + (size_t)o * CK + quad * 8 + t * 32;
            float4 b0 = *(const float4*)brow;
            float4 b1 = *(const float4*)(brow + 4);
            union { short8 s8; unsigned short u[8]; } bfu;
            bfu.u[0] = f2bf(b0.x); bfu.u[1] = f2bf(b0.y); bfu.u[2] = f2bf(b0.z); bfu.u[3] = f2bf(b0.w);
            bfu.u[4] = f2bf(b1.x); bfu.u[5] = f2bf(b1.y); bfu.u[6] = f2bf(b1.z); bfu.u[7] = f2bf(b1.w);
            bfrag = bfu.s8;
        }
        acc = __builtin_amdgcn_mfma_f32_16x16x32_bf16(afrag, bfrag, acc, 0, 0, 0);
    }
    const float bias = db[o];
    const int px0 = quad << 2;                    // row = quad*4 + reg
    float4 res;
    res.x = acc[0] + bias; res.y = acc[1] + bias; res.z = acc[2] + bias; res.w = acc[3] + bias;
    *(float4*)(out + ((size_t)(b * COUT_ + o) * H_ + h) * W_ + w0 + px0) = res;
}

extern "C" void kernel_launch(void* const* d_in, const int* in_sizes, int n_in,
                              void* d_out, int out_size, void* d_ws, size_t ws_size,
                              hipStream_t stream) {
    (void)in_sizes; (void)n_in; (void)out_size;
    const float* x  = (const float*)d_in[0];
    const float* ow = (const float*)d_in[1];
    const float* ob = (const float*)d_in[2];
    const float* dw = (const float*)d_in[3];
    const float* db = (const float*)d_in[4];
    float* outp = (float*)d_out;

    const size_t xbytes  = (size_t)B_ * C_ * H_ * W_ * sizeof(float);
    const size_t dwbytes = (size_t)CK * COUT_ * sizeof(unsigned short);
    const size_t owbytes = (size_t)NW81 * sizeof(unsigned int);
    const dim3 grid(B_ * H_ * (W_ / TPX)), blk(256);
    const int dwblocks = (CK * COUT_) / 256;     // 144
    const int owblocks = (NW81 + 255) / 256;     // 21

    if (ws_size >= xbytes + dwbytes + owbytes) {
        float* xt = (float*)d_ws;
        unsigned short* dwb = (unsigned short*)((char*)d_ws + xbytes);
        unsigned int* owp = (unsigned int*)((char*)d_ws + xbytes + dwbytes);
        nchw_to_nhwc<<<dim3(B_ * H_ * 2), blk, 0, stream>>>(x, xt);
        prep_weights<<<dim3(dwblocks + owblocks), blk, 0, stream>>>(dw, dwb, ow, owp);
        dcn_fused<true, true, true><<<grid, blk, 0, stream>>>(xt, ow, owp, ob, dw, dwb, db, outp);
    } else if (ws_size >= xbytes + dwbytes) {
        float* xt = (float*)d_ws;
        unsigned short* dwb = (unsigned short*)((char*)d_ws + xbytes);
        nchw_to_nhwc<<<dim3(B_ * H_ * 2), blk, 0, stream>>>(x, xt);
        prep_weights<<<dim3(dwblocks), blk, 0, stream>>>(dw, dwb, nullptr, nullptr);
        dcn_fused<true, true, false><<<grid, blk, 0, stream>>>(xt, ow, nullptr, ob, dw, dwb, db, outp);
    } else if (ws_size >= xbytes) {
        float* xt = (float*)d_ws;
        nchw_to_nhwc<<<dim3(B_ * H_ * 2), blk, 0, stream>>>(x, xt);
        dcn_fused<true, false, false><<<grid, blk, 0, stream>>>(xt, ow, nullptr, ob, dw, nullptr, db, outp);
    } else {
        dcn_fused<false, false, false><<<grid, blk, 0, stream>>>(x, ow, nullptr, ob, dw, nullptr, db, outp);
    }
}